// Round 8
// baseline (160.730 us; speedup 1.0000x reference)
//
#include <hip/hip_runtime.h>
#include <stdint.h>

#define B_ 2
#define C_ 256
#define H_ 96
#define W_ 96
#define HW_ (H_*W_)

typedef _Float16 half8 __attribute__((ext_vector_type(8)));
typedef float f32x4 __attribute__((ext_vector_type(4)));
typedef unsigned int u32x4 __attribute__((ext_vector_type(4)));

// ---- workspace byte layout ----
#define F1OFF   0u          // f16 (B,HW,C) f1, pre-scaled 1/16   9,437,184 B
#define L0OFF   9437184u    // f16 pyramid level 0 (B,h,w,C)
#define L1OFF   18874368u
#define L2OFF   21233664u
#define L3OFF   21823488u
#define SCROFF  21970944u   // f16 scr[B*HW][324]                11,943,936 B
#define CNTOFF  33914880u   // int cnt[1152]
#define OFFOFF  33919488u   // int offs[1153]
#define CUROFF  33924104u   // int cursor[1152]
#define PERMOFF 33928712u   // int perm[18432]

#define SLAB_ROWS 112
#define SLAB_STR  264       // halves per slab row (528 B)
#define DLW       176       // dl columns

// ---------- (B, C, HW) f32 -> (B, HW, C) f16 transpose (+scale) ----------
__global__ __launch_bounds__(256) void k_transpose(const float* __restrict__ in,
                                                   _Float16* __restrict__ out,
                                                   float scale) {
  __shared__ float t[32][33];
  const int b = blockIdx.z;
  const int p0 = blockIdx.x * 32, c0 = blockIdx.y * 32;
  const int tx = threadIdx.x, ty = threadIdx.y;
  const float* src = in + ((size_t)b * C_ + c0) * HW_ + p0;
#pragma unroll
  for (int i = 0; i < 4; ++i)
    t[ty + 8 * i][tx] = src[(size_t)(ty + 8 * i) * HW_ + tx];
  __syncthreads();
  _Float16* dst = out + ((size_t)b * HW_ + p0) * C_ + c0;
#pragma unroll
  for (int i = 0; i < 4; ++i)
    dst[(size_t)(ty + 8 * i) * C_ + tx] = (_Float16)(t[tx][ty + 8 * i] * scale);
}

// ---------- 2x2 avg pool on (B, h, w, C) f16 ----------
__global__ __launch_bounds__(256) void k_pool(const _Float16* __restrict__ in,
                                              _Float16* __restrict__ out,
                                              int hin, int win) {
  const int wout = win >> 1, hout = hin >> 1;
  int idx = blockIdx.x;
  const int X = idx % wout; idx /= wout;
  const int Y = idx % hout; const int b = idx / hout;
  const int c = threadIdx.x;
  const _Float16* p = in + (((size_t)b * hin + 2 * Y) * win + 2 * X) * C_ + c;
  const size_t rs = (size_t)win * C_;
  float v = (float)p[0] + (float)p[C_] + (float)p[rs] + (float)p[rs + C_];
  out[(((size_t)b * hout + Y) * wout + X) * C_ + c] = (_Float16)(v * 0.25f);
}

// ---------- bucket prepass: histogram / scan / scatter ----------
__device__ __forceinline__ int cell_of(float cx, float cy, int b) {
  int ci = (int)(cx * 0.25f); ci = min(max(ci, 0), 23);
  int cj = (int)(cy * 0.25f); cj = min(max(cj, 0), 23);
  return b * 576 + cj * 24 + ci;
}

__global__ __launch_bounds__(256) void k_hist(const float* __restrict__ cent,
                                              int* __restrict__ cnt) {
  const int t = blockIdx.x * 256 + threadIdx.x;
  const int b = t / HW_, yx = t - b * HW_;
  const float cx = cent[(size_t)b * 2 * HW_ + yx];
  const float cy = cent[(size_t)b * 2 * HW_ + HW_ + yx];
  atomicAdd(&cnt[cell_of(cx, cy, b)], 1);
}

__global__ __launch_bounds__(1024) void k_scan(const int* __restrict__ cnt,
                                               int* __restrict__ offs,
                                               int* __restrict__ cursor) {
  __shared__ int sh[2048];
  const int t = threadIdx.x;
  sh[t] = (t < 1152) ? cnt[t] : 0;
  sh[t + 1024] = ((t + 1024) < 1152) ? cnt[t + 1024] : 0;
  __syncthreads();
  for (int d = 1; d < 2048; d <<= 1) {
    const int v0 = (t >= d) ? sh[t - d] : 0;
    const int v1 = ((t + 1024) >= d) ? sh[t + 1024 - d] : 0;
    __syncthreads();
    sh[t] += v0; sh[t + 1024] += v1;
    __syncthreads();
  }
  if (t == 0) offs[0] = 0;
  if (t < 1152) { offs[t + 1] = sh[t]; cursor[t] = (t == 0) ? 0 : sh[t - 1]; }
  const int t2 = t + 1024;
  if (t2 < 1152) { offs[t2 + 1] = sh[t2]; cursor[t2] = sh[t2 - 1]; }
}

__global__ __launch_bounds__(256) void k_scatter(const float* __restrict__ cent,
                                                 int* __restrict__ cursor,
                                                 int* __restrict__ perm) {
  const int t = blockIdx.x * 256 + threadIdx.x;
  const int b = t / HW_, yx = t - b * HW_;
  const float cx = cent[(size_t)b * 2 * HW_ + yx];
  const float cy = cent[(size_t)b * 2 * HW_ + HW_ + yx];
  const int pos = atomicAdd(&cursor[cell_of(cx, cy, b)], 1);
  perm[pos] = t;
}

// ---------- main: per-cell chunked slab GEMM (MFMA, M=32) ----------
__global__ __launch_bounds__(512, 4) void k_cell(char* __restrict__ ws,
                                                 const float* __restrict__ cent) {
  __shared__ _Float16 slab[SLAB_ROWS * SLAB_STR];  // 59.1 KB
  __shared__ _Float16 dlh[32 * DLW];               // 11.0 KB

  const int cell = blockIdx.x;
  const int b = cell / 576;
  const int cib = cell - b * 576;
  const int ci = cib % 24, cj = cib / 24;

  const int* offs = (const int*)(ws + OFFOFF);
  const int* perm = (const int*)(ws + PERMOFF);
  const int beg = offs[cell], end = offs[cell + 1];
  if (beg == end) return;
  const int npix = end - beg;
  const int nmt = (npix + 31) >> 5;

  const int t = threadIdx.x;
  const int w = t >> 6, lane = t & 63;
  const int row16 = lane & 15, kb = lane >> 4;

  const uint32_t LB[4] = {L0OFF, L1OFF, L2OFF, L3OFF};
  const uint32_t PBl[4] = {4718592u, 1179648u, 294912u, 73728u};
  const int Wt[4] = {13, 11, 10, 10};

  _Float16* scr = (_Float16*)(ws + SCROFF);
  const char* f1b = ws + F1OFF;

  for (int lvl = 0; lvl < 4; ++lvl) {
    const int wl = 96 >> lvl;
    const int W = Wt[lvl];
    const int N = W * W;
    const int FX = (lvl < 3) ? (ci << (2 - lvl)) : (ci >> 1);
    const int FY = (lvl < 3) ? (cj << (2 - lvl)) : (cj >> 1);
    const int XU0 = FX - 4, YU0 = FY - 4;
    const char* lbase = ws + LB[lvl] + (size_t)b * PBl[lvl];

    for (int mt = 0; mt < nmt; ++mt) {
      // A-fragments for 32 pixels straight from L2 into regs
      half8 av0[8], av1[8];
      {
        const int i0 = beg + mt * 32 + row16;
        const int i1 = i0 + 16;
        const int pv0 = (i0 < end) ? perm[i0] : perm[beg];
        const int pv1 = (i1 < end) ? perm[i1] : perm[beg];
        const char* a0 = f1b + (size_t)pv0 * 512 + kb * 16;
        const char* a1 = f1b + (size_t)pv1 * 512 + kb * 16;
#pragma unroll
        for (int k = 0; k < 8; ++k) {
          av0[k] = *(const half8*)(a0 + k * 64);
          av1[k] = *(const half8*)(a1 + k * 64);
        }
      }

      for (int base = 0; base < N; base += SLAB_ROWS) {
        const int len = min(N - base, SLAB_ROWS);
        const int rows_pad = (len + 15) & ~15;

        __syncthreads();   // slab/dl safe to overwrite
        // stage chunk (zero-fill OOB and phantom rows)
        const int nseg = rows_pad * 32;
        for (int s = t; s < nseg; s += 512) {
          const int pl = s >> 5, seg = s & 31;
          const int gp = base + pl;
          const int sy = gp / W, sx = gp - sy * W;
          const int gy = YU0 + sy, gx = XU0 + sx;
          u32x4 v = {0, 0, 0, 0};
          if (pl < len && gy >= 0 && gy < wl && gx >= 0 && gx < wl)
            v = *(const u32x4*)(lbase + (((size_t)gy * wl + gx) << 9) + seg * 16);
          *(u32x4*)&slab[pl * SLAB_STR + seg * 8] = v;
        }
        __syncthreads();

        // GEMM chunk: dl[px][base + n] over rows_pad positions
        const int ntiles = rows_pad >> 4;
        for (int jj = w; jj < ntiles; jj += 8) {
          const int ln0 = jj * 16;
          f32x4 acc0 = {0.f, 0.f, 0.f, 0.f};
          f32x4 acc1 = {0.f, 0.f, 0.f, 0.f};
          const _Float16* bp = &slab[(ln0 + row16) * SLAB_STR + kb * 8];
#pragma unroll
          for (int k = 0; k < 8; ++k) {
            const half8 bv = *(const half8*)(bp + k * 32);
            acc0 = __builtin_amdgcn_mfma_f32_16x16x32_f16(av0[k], bv, acc0, 0, 0, 0);
            acc1 = __builtin_amdgcn_mfma_f32_16x16x32_f16(av1[k], bv, acc1, 0, 0, 0);
          }
          const int col = base + ln0 + row16;
#pragma unroll
          for (int j4 = 0; j4 < 4; ++j4) {
            dlh[(kb * 4 + j4) * DLW + col]      = (_Float16)acc0[j4];
            dlh[(kb * 4 + j4 + 16) * DLW + col] = (_Float16)acc1[j4];
          }
        }
      }
      __syncthreads();

      // bilinear epilogue -> scr[pix][lvl*81 + o]; 16 threads per pixel
      {
        const int p = t >> 4, q = t & 15;
        const int idx = beg + mt * 32 + p;
        if (idx < end) {
          const int pv = perm[idx];
          const int yx = pv - b * HW_;
          const float cx = cent[(size_t)b * 2 * HW_ + yx];
          const float cy = cent[(size_t)b * 2 * HW_ + HW_ + yx];
          const float inv = 1.0f / (float)(1 << lvl);
          const float cxl = cx * inv, cyl = cy * inv;
          const float fxl = floorf(cxl), fyl = floorf(cyl);
          const float wx1 = cxl - fxl, wy1 = cyl - fyl;
          const float wx0 = 1.f - wx1, wy0 = 1.f - wy1;
          const int sxp = (int)fxl - FX, syp = (int)fyl - FY;
          const _Float16* d = &dlh[p * DLW];
          _Float16* so = scr + (size_t)pv * 324 + lvl * 81;
#pragma unroll
          for (int rr = 0; rr < 6; ++rr) {
            const int o = q + rr * 16;
            if (o < 81) {
              const int a = o / 9, bq = o - a * 9;   // a = x idx, bq = y idx
              const int n = (syp + bq) * W + sxp + a;
              const float d00 = (float)d[n], d10 = (float)d[n + 1];
              const float d01 = (float)d[n + W], d11 = (float)d[n + W + 1];
              so[o] = (_Float16)(wy0 * (wx0 * d00 + wx1 * d10) +
                                 wy1 * (wx0 * d01 + wx1 * d11));
            }
          }
        }
      }
      __syncthreads();
    }
  }
}

// ---------- final transpose: scr[B*HW][324] f16 -> out[B][324][HW] f32 ----------
__global__ __launch_bounds__(256) void k_otrans(const _Float16* __restrict__ scr,
                                                float* __restrict__ out) {
  __shared__ float t[32][33];
  const int b = blockIdx.z;
  const int yx0 = blockIdx.x * 32, c0 = blockIdx.y * 32;
  const int tx = threadIdx.x, ty = threadIdx.y;
#pragma unroll
  for (int i = 0; i < 4; ++i) {
    const int yxi = ty + 8 * i, c = c0 + tx;
    t[yxi][tx] = (c < 324)
        ? (float)scr[((size_t)b * HW_ + yx0 + yxi) * 324 + c] : 0.f;
  }
  __syncthreads();
#pragma unroll
  for (int i = 0; i < 4; ++i) {
    const int c = c0 + ty + 8 * i;
    if (c < 324)
      out[((size_t)b * 324 + c) * HW_ + yx0 + tx] = t[tx][ty + 8 * i];
  }
}

extern "C" void kernel_launch(void* const* d_in, const int* in_sizes, int n_in,
                              void* d_out, int out_size, void* d_ws, size_t ws_size,
                              hipStream_t stream) {
  (void)in_sizes; (void)n_in; (void)out_size; (void)ws_size;
  const float* f1   = (const float*)d_in[0];
  const float* f2   = (const float*)d_in[1];
  const float* cent = (const float*)d_in[2];
  float* out = (float*)d_out;

  char* ws = (char*)d_ws;
  _Float16* f1t = (_Float16*)(ws + F1OFF);
  _Float16* L0  = (_Float16*)(ws + L0OFF);
  _Float16* L1  = (_Float16*)(ws + L1OFF);
  _Float16* L2  = (_Float16*)(ws + L2OFF);
  _Float16* L3  = (_Float16*)(ws + L3OFF);
  int* cnt    = (int*)(ws + CNTOFF);
  int* offs   = (int*)(ws + OFFOFF);
  int* cursor = (int*)(ws + CUROFF);
  int* perm   = (int*)(ws + PERMOFF);

  (void)hipMemsetAsync(cnt, 0, 1152 * sizeof(int), stream);

  dim3 tb(32, 8, 1);
  dim3 tg(HW_ / 32, C_ / 32, B_);
  hipLaunchKernelGGL(k_transpose, tg, tb, 0, stream, f1, f1t, 0.0625f);
  hipLaunchKernelGGL(k_transpose, tg, tb, 0, stream, f2, L0, 1.0f);
  hipLaunchKernelGGL(k_pool, dim3(B_ * 48 * 48), dim3(256), 0, stream, L0, L1, 96, 96);
  hipLaunchKernelGGL(k_pool, dim3(B_ * 24 * 24), dim3(256), 0, stream, L1, L2, 48, 48);
  hipLaunchKernelGGL(k_pool, dim3(B_ * 12 * 12), dim3(256), 0, stream, L2, L3, 24, 24);

  hipLaunchKernelGGL(k_hist, dim3(72), dim3(256), 0, stream, cent, cnt);
  hipLaunchKernelGGL(k_scan, dim3(1), dim3(1024), 0, stream, cnt, offs, cursor);
  hipLaunchKernelGGL(k_scatter, dim3(72), dim3(256), 0, stream, cent, cursor, perm);

  hipLaunchKernelGGL(k_cell, dim3(1152), dim3(512), 0, stream, ws, cent);

  hipLaunchKernelGGL(k_otrans, dim3(HW_ / 32, 11, B_), tb, 0, stream,
                     (const _Float16*)(ws + SCROFF), out);
}

// Round 9
// 134.886 us; speedup vs baseline: 1.1916x; 1.1916x over previous
//
#include <hip/hip_runtime.h>
#include <stdint.h>

#define B_ 2
#define C_ 256
#define H_ 96
#define W_ 96
#define HW_ (H_*W_)

typedef _Float16 half8 __attribute__((ext_vector_type(8)));
typedef float f32x4 __attribute__((ext_vector_type(4)));
typedef unsigned int u32x4 __attribute__((ext_vector_type(4)));

// ---- workspace byte layout: [zero page 512][f1t][L0][L1][L2][L3][scr][cnt][offs][cursor][perm]
#define ZPOFF   0u
#define F1OFF   512u
#define L0OFF   9437696u
#define L1OFF   18874880u
#define L2OFF   21234176u
#define L3OFF   21824000u
#define SCROFF  21971456u
#define CNTOFF  33915392u
#define OFFOFF  33920000u
#define CUROFF  33924616u
#define PERMOFF 33929224u

#define DLW 176

// ---------- (B, C, HW) f32 -> (B, HW, C) f16 transpose (+scale) ----------
__global__ __launch_bounds__(256) void k_transpose(const float* __restrict__ in,
                                                   _Float16* __restrict__ out,
                                                   float scale) {
  __shared__ float t[32][33];
  const int b = blockIdx.z;
  const int p0 = blockIdx.x * 32, c0 = blockIdx.y * 32;
  const int tx = threadIdx.x, ty = threadIdx.y;
  const float* src = in + ((size_t)b * C_ + c0) * HW_ + p0;
#pragma unroll
  for (int i = 0; i < 4; ++i)
    t[ty + 8 * i][tx] = src[(size_t)(ty + 8 * i) * HW_ + tx];
  __syncthreads();
  _Float16* dst = out + ((size_t)b * HW_ + p0) * C_ + c0;
#pragma unroll
  for (int i = 0; i < 4; ++i)
    dst[(size_t)(ty + 8 * i) * C_ + tx] = (_Float16)(t[tx][ty + 8 * i] * scale);
}

// ---------- 2x2 avg pool on (B, h, w, C) f16 ----------
__global__ __launch_bounds__(256) void k_pool(const _Float16* __restrict__ in,
                                              _Float16* __restrict__ out,
                                              int hin, int win) {
  const int wout = win >> 1, hout = hin >> 1;
  int idx = blockIdx.x;
  const int X = idx % wout; idx /= wout;
  const int Y = idx % hout; const int b = idx / hout;
  const int c = threadIdx.x;
  const _Float16* p = in + (((size_t)b * hin + 2 * Y) * win + 2 * X) * C_ + c;
  const size_t rs = (size_t)win * C_;
  float v = (float)p[0] + (float)p[C_] + (float)p[rs] + (float)p[rs + C_];
  out[(((size_t)b * hout + Y) * wout + X) * C_ + c] = (_Float16)(v * 0.25f);
}

// ---------- bucket prepass: histogram / scan / scatter ----------
__device__ __forceinline__ int cell_of(float cx, float cy, int b) {
  int ci = (int)(cx * 0.25f); ci = min(max(ci, 0), 23);
  int cj = (int)(cy * 0.25f); cj = min(max(cj, 0), 23);
  return b * 576 + cj * 24 + ci;
}

__global__ __launch_bounds__(256) void k_hist(const float* __restrict__ cent,
                                              int* __restrict__ cnt) {
  const int t = blockIdx.x * 256 + threadIdx.x;
  const int b = t / HW_, yx = t - b * HW_;
  const float cx = cent[(size_t)b * 2 * HW_ + yx];
  const float cy = cent[(size_t)b * 2 * HW_ + HW_ + yx];
  atomicAdd(&cnt[cell_of(cx, cy, b)], 1);
}

__global__ __launch_bounds__(1024) void k_scan(const int* __restrict__ cnt,
                                               int* __restrict__ offs,
                                               int* __restrict__ cursor) {
  __shared__ int sh[2048];
  const int t = threadIdx.x;
  sh[t] = (t < 1152) ? cnt[t] : 0;
  sh[t + 1024] = ((t + 1024) < 1152) ? cnt[t + 1024] : 0;
  __syncthreads();
  for (int d = 1; d < 2048; d <<= 1) {
    const int v0 = (t >= d) ? sh[t - d] : 0;
    const int v1 = ((t + 1024) >= d) ? sh[t + 1024 - d] : 0;
    __syncthreads();
    sh[t] += v0; sh[t + 1024] += v1;
    __syncthreads();
  }
  if (t == 0) offs[0] = 0;
  if (t < 1152) { offs[t + 1] = sh[t]; cursor[t] = (t == 0) ? 0 : sh[t - 1]; }
  const int t2 = t + 1024;
  if (t2 < 1152) { offs[t2 + 1] = sh[t2]; cursor[t2] = sh[t2 - 1]; }
}

__global__ __launch_bounds__(256) void k_scatter(const float* __restrict__ cent,
                                                 int* __restrict__ cursor,
                                                 int* __restrict__ perm) {
  const int t = blockIdx.x * 256 + threadIdx.x;
  const int b = t / HW_, yx = t - b * HW_;
  const float cx = cent[(size_t)b * 2 * HW_ + yx];
  const float cy = cent[(size_t)b * 2 * HW_ + HW_ + yx];
  const int pos = atomicAdd(&cursor[cell_of(cx, cy, b)], 1);
  perm[pos] = t;
}

// ---------- main: per-cell GEMM, B-fragments gathered straight from L2 ----------
__global__ __launch_bounds__(256, 4) void k_cell(char* __restrict__ ws,
                                                 const float* __restrict__ cent) {
  __shared__ _Float16 dlh[32 * DLW];   // 11.3 KB: px x pos result tile

  const int cell = blockIdx.x;
  const int b = cell / 576;
  const int cib = cell - b * 576;
  const int ci = cib % 24, cj = cib / 24;

  const int* offs = (const int*)(ws + OFFOFF);
  const int* perm = (const int*)(ws + PERMOFF);
  const int beg = offs[cell], end = offs[cell + 1];
  if (beg == end) return;
  const int npix = end - beg;
  const int nmt = (npix + 31) >> 5;

  const int t = threadIdx.x;
  const int w = t >> 6, lane = t & 63;
  const int row16 = lane & 15, kb = lane >> 4;

  const char* f1b = ws + F1OFF;
  const char* zp  = ws + ZPOFF;
  _Float16* scr = (_Float16*)(ws + SCROFF);

  constexpr uint32_t LB[4]  = {L0OFF, L1OFF, L2OFF, L3OFF};
  constexpr uint32_t PBl[4] = {4718592u, 1179648u, 294912u, 73728u};
  constexpr int Wt[4] = {13, 11, 10, 10};

  for (int mt = 0; mt < nmt; ++mt) {
    // A-fragments: 32 pixels straight from L2 into regs (shared across levels)
    half8 av0[8], av1[8];
    {
      const int i0 = beg + mt * 32 + row16;
      const int i1 = i0 + 16;
      const int pv0 = (i0 < end) ? perm[i0] : perm[beg];
      const int pv1 = (i1 < end) ? perm[i1] : perm[beg];
      const char* a0 = f1b + (size_t)pv0 * 512 + kb * 16;
      const char* a1 = f1b + (size_t)pv1 * 512 + kb * 16;
#pragma unroll
      for (int k = 0; k < 8; ++k) {
        av0[k] = *(const half8*)(a0 + k * 64);
        av1[k] = *(const half8*)(a1 + k * 64);
      }
    }

#pragma unroll
    for (int lvl = 0; lvl < 4; ++lvl) {
      const int wl = 96 >> lvl;
      const int W = Wt[lvl];
      const int N = W * W;
      const int ntiles = (N + 15) >> 4;
      const int FX = (lvl < 3) ? (ci << (2 - lvl)) : (ci >> 1);
      const int FY = (lvl < 3) ? (cj << (2 - lvl)) : (cj >> 1);
      const int XU0 = FX - 4, YU0 = FY - 4;
      const char* lbase = ws + LB[lvl] + (size_t)b * PBl[lvl];

      // GEMM: each wave owns N-tiles j = w, w+4, ...
      for (int j = w; j < ntiles; j += 4) {
        const int n = j * 16 + row16;
        const int sy = n / W, sx = n - sy * W;        // W literal (unrolled lvl)
        const int gy = YU0 + sy, gx = XU0 + sx;
        const bool val = (gy >= 0) & (gy < wl) & (gx >= 0) & (gx < wl);
        const char* bbase = val ? (lbase + (((size_t)(gy * wl + gx)) << 9)) : zp;
        const char* bp = bbase + kb * 16;
        f32x4 acc0 = {0.f, 0.f, 0.f, 0.f};
        f32x4 acc1 = {0.f, 0.f, 0.f, 0.f};
#pragma unroll
        for (int k = 0; k < 8; ++k) {
          const half8 bv = *(const half8*)(bp + k * 64);
          acc0 = __builtin_amdgcn_mfma_f32_16x16x32_f16(av0[k], bv, acc0, 0, 0, 0);
          acc1 = __builtin_amdgcn_mfma_f32_16x16x32_f16(av1[k], bv, acc1, 0, 0, 0);
        }
#pragma unroll
        for (int j4 = 0; j4 < 4; ++j4) {
          dlh[(kb * 4 + j4) * DLW + n]        = (_Float16)acc0[j4];
          dlh[(kb * 4 + j4 + 16) * DLW + n]   = (_Float16)acc1[j4];
        }
      }
      __syncthreads();

      // bilinear epilogue -> scr[pix][lvl*81 + o]; 8 threads per pixel
      {
        const int p = t >> 3, q = t & 7;
        const int idx = beg + mt * 32 + p;
        if (idx < end) {
          const int pv = perm[idx];
          const int yx = pv - b * HW_;
          const float cx = cent[(size_t)b * 2 * HW_ + yx];
          const float cy = cent[(size_t)b * 2 * HW_ + HW_ + yx];
          const float inv = 1.0f / (float)(1 << lvl);
          const float cxl = cx * inv, cyl = cy * inv;
          const float fxl = floorf(cxl), fyl = floorf(cyl);
          const float wx1 = cxl - fxl, wy1 = cyl - fyl;
          const float wx0 = 1.f - wx1, wy0 = 1.f - wy1;
          const int sxp = (int)fxl - FX, syp = (int)fyl - FY;
          const _Float16* d = &dlh[p * DLW];
          _Float16* so = scr + (size_t)pv * 324 + lvl * 81;
#pragma unroll
          for (int rr = 0; rr < 11; ++rr) {
            const int o = q + rr * 8;
            if (o < 81) {
              const int a = o / 9, bq = o - a * 9;   // a = x idx, bq = y idx
              const int n = (syp + bq) * W + sxp + a;
              const float d00 = (float)d[n], d10 = (float)d[n + 1];
              const float d01 = (float)d[n + W], d11 = (float)d[n + W + 1];
              so[o] = (_Float16)(wy0 * (wx0 * d00 + wx1 * d10) +
                                 wy1 * (wx0 * d01 + wx1 * d11));
            }
          }
        }
      }
      __syncthreads();
    }
  }
}

// ---------- final transpose: scr[B*HW][324] f16 -> out[B][324][HW] f32 ----------
__global__ __launch_bounds__(256) void k_otrans(const _Float16* __restrict__ scr,
                                                float* __restrict__ out) {
  __shared__ float t[32][33];
  const int b = blockIdx.z;
  const int yx0 = blockIdx.x * 32, c0 = blockIdx.y * 32;
  const int tx = threadIdx.x, ty = threadIdx.y;
#pragma unroll
  for (int i = 0; i < 4; ++i) {
    const int yxi = ty + 8 * i, c = c0 + tx;
    t[yxi][tx] = (c < 324)
        ? (float)scr[((size_t)b * HW_ + yx0 + yxi) * 324 + c] : 0.f;
  }
  __syncthreads();
#pragma unroll
  for (int i = 0; i < 4; ++i) {
    const int c = c0 + ty + 8 * i;
    if (c < 324)
      out[((size_t)b * 324 + c) * HW_ + yx0 + tx] = t[tx][ty + 8 * i];
  }
}

extern "C" void kernel_launch(void* const* d_in, const int* in_sizes, int n_in,
                              void* d_out, int out_size, void* d_ws, size_t ws_size,
                              hipStream_t stream) {
  (void)in_sizes; (void)n_in; (void)out_size; (void)ws_size;
  const float* f1   = (const float*)d_in[0];
  const float* f2   = (const float*)d_in[1];
  const float* cent = (const float*)d_in[2];
  float* out = (float*)d_out;

  char* ws = (char*)d_ws;
  _Float16* f1t = (_Float16*)(ws + F1OFF);
  _Float16* L0  = (_Float16*)(ws + L0OFF);
  _Float16* L1  = (_Float16*)(ws + L1OFF);
  _Float16* L2  = (_Float16*)(ws + L2OFF);
  _Float16* L3  = (_Float16*)(ws + L3OFF);
  int* cnt    = (int*)(ws + CNTOFF);
  int* offs   = (int*)(ws + OFFOFF);
  int* cursor = (int*)(ws + CUROFF);
  int* perm   = (int*)(ws + PERMOFF);

  (void)hipMemsetAsync(ws + ZPOFF, 0, 512, stream);            // zero page
  (void)hipMemsetAsync(cnt, 0, 1152 * sizeof(int), stream);

  dim3 tb(32, 8, 1);
  dim3 tg(HW_ / 32, C_ / 32, B_);
  hipLaunchKernelGGL(k_transpose, tg, tb, 0, stream, f1, f1t, 0.0625f);
  hipLaunchKernelGGL(k_transpose, tg, tb, 0, stream, f2, L0, 1.0f);
  hipLaunchKernelGGL(k_pool, dim3(B_ * 48 * 48), dim3(256), 0, stream, L0, L1, 96, 96);
  hipLaunchKernelGGL(k_pool, dim3(B_ * 24 * 24), dim3(256), 0, stream, L1, L2, 48, 48);
  hipLaunchKernelGGL(k_pool, dim3(B_ * 12 * 12), dim3(256), 0, stream, L2, L3, 24, 24);

  hipLaunchKernelGGL(k_hist, dim3(72), dim3(256), 0, stream, cent, cnt);
  hipLaunchKernelGGL(k_scan, dim3(1), dim3(1024), 0, stream, cnt, offs, cursor);
  hipLaunchKernelGGL(k_scatter, dim3(72), dim3(256), 0, stream, cent, cursor, perm);

  hipLaunchKernelGGL(k_cell, dim3(1152), dim3(256), 0, stream, ws, cent);

  hipLaunchKernelGGL(k_otrans, dim3(HW_ / 32, 11, B_), tb, 0, stream,
                     (const _Float16*)(ws + SCROFF), out);
}

// Round 10
// 123.977 us; speedup vs baseline: 1.2964x; 1.0880x over previous
//
#include <hip/hip_runtime.h>
#include <stdint.h>

#define B_ 2
#define C_ 256
#define H_ 96
#define W_ 96
#define HW_ (H_*W_)

typedef _Float16 half8 __attribute__((ext_vector_type(8)));
typedef float f32x4 __attribute__((ext_vector_type(4)));

// ---- workspace byte layout: [zero page 512][f1t][L0][L1][L2][L3][scr][cnt][offs][cursor][perm]
#define ZPOFF   0u
#define F1OFF   512u
#define L0OFF   9437696u
#define L1OFF   18874880u
#define L2OFF   21234176u
#define L3OFF   21824000u
#define SCROFF  21971456u
#define CNTOFF  33915392u
#define OFFOFF  33920000u
#define CUROFF  33924616u
#define PERMOFF 33929224u

#define DLW 176

// ---------- (B, C, HW) f32 -> (B, HW, C) f16 transpose (+scale) ----------
__global__ __launch_bounds__(256) void k_transpose(const float* __restrict__ in,
                                                   _Float16* __restrict__ out,
                                                   float scale) {
  __shared__ float t[32][33];
  const int b = blockIdx.z;
  const int p0 = blockIdx.x * 32, c0 = blockIdx.y * 32;
  const int tx = threadIdx.x, ty = threadIdx.y;
  const float* src = in + ((size_t)b * C_ + c0) * HW_ + p0;
#pragma unroll
  for (int i = 0; i < 4; ++i)
    t[ty + 8 * i][tx] = src[(size_t)(ty + 8 * i) * HW_ + tx];
  __syncthreads();
  _Float16* dst = out + ((size_t)b * HW_ + p0) * C_ + c0;
#pragma unroll
  for (int i = 0; i < 4; ++i)
    dst[(size_t)(ty + 8 * i) * C_ + tx] = (_Float16)(t[tx][ty + 8 * i] * scale);
}

// ---------- 2x2 avg pool on (B, h, w, C) f16 ----------
__global__ __launch_bounds__(256) void k_pool(const _Float16* __restrict__ in,
                                              _Float16* __restrict__ out,
                                              int hin, int win) {
  const int wout = win >> 1, hout = hin >> 1;
  int idx = blockIdx.x;
  const int X = idx % wout; idx /= wout;
  const int Y = idx % hout; const int b = idx / hout;
  const int c = threadIdx.x;
  const _Float16* p = in + (((size_t)b * hin + 2 * Y) * win + 2 * X) * C_ + c;
  const size_t rs = (size_t)win * C_;
  float v = (float)p[0] + (float)p[C_] + (float)p[rs] + (float)p[rs + C_];
  out[(((size_t)b * hout + Y) * wout + X) * C_ + c] = (_Float16)(v * 0.25f);
}

// ---------- bucket prepass: histogram / scan / scatter ----------
__device__ __forceinline__ int cell_of(float cx, float cy, int b) {
  int ci = (int)(cx * 0.25f); ci = min(max(ci, 0), 23);
  int cj = (int)(cy * 0.25f); cj = min(max(cj, 0), 23);
  return b * 576 + cj * 24 + ci;
}

__global__ __launch_bounds__(256) void k_hist(const float* __restrict__ cent,
                                              int* __restrict__ cnt) {
  const int t = blockIdx.x * 256 + threadIdx.x;
  const int b = t / HW_, yx = t - b * HW_;
  const float cx = cent[(size_t)b * 2 * HW_ + yx];
  const float cy = cent[(size_t)b * 2 * HW_ + HW_ + yx];
  atomicAdd(&cnt[cell_of(cx, cy, b)], 1);
}

__global__ __launch_bounds__(1024) void k_scan(const int* __restrict__ cnt,
                                               int* __restrict__ offs,
                                               int* __restrict__ cursor) {
  __shared__ int sh[2048];
  const int t = threadIdx.x;
  sh[t] = (t < 1152) ? cnt[t] : 0;
  sh[t + 1024] = ((t + 1024) < 1152) ? cnt[t + 1024] : 0;
  __syncthreads();
  for (int d = 1; d < 2048; d <<= 1) {
    const int v0 = (t >= d) ? sh[t - d] : 0;
    const int v1 = ((t + 1024) >= d) ? sh[t + 1024 - d] : 0;
    __syncthreads();
    sh[t] += v0; sh[t + 1024] += v1;
    __syncthreads();
  }
  if (t == 0) offs[0] = 0;
  if (t < 1152) { offs[t + 1] = sh[t]; cursor[t] = (t == 0) ? 0 : sh[t - 1]; }
  const int t2 = t + 1024;
  if (t2 < 1152) { offs[t2 + 1] = sh[t2]; cursor[t2] = sh[t2 - 1]; }
}

__global__ __launch_bounds__(256) void k_scatter(const float* __restrict__ cent,
                                                 int* __restrict__ cursor,
                                                 int* __restrict__ perm) {
  const int t = blockIdx.x * 256 + threadIdx.x;
  const int b = t / HW_, yx = t - b * HW_;
  const float cx = cent[(size_t)b * 2 * HW_ + yx];
  const float cy = cent[(size_t)b * 2 * HW_ + HW_ + yx];
  const int pos = atomicAdd(&cursor[cell_of(cx, cy, b)], 1);
  perm[pos] = t;
}

// ---------- per-(cell,level) single-wave GEMM + epilogue ----------
template <int LVL>
__device__ __forceinline__ void cell_level(char* __restrict__ ws,
                                           const float* __restrict__ cent,
                                           int b, int ci, int cj,
                                           int beg, int end,
                                           _Float16* __restrict__ dl, int lane) {
  constexpr int wl = 96 >> LVL;
  constexpr int W = (LVL == 0) ? 13 : (LVL == 1) ? 11 : 10;
  constexpr int N = W * W;
  constexpr int ntiles = (N + 15) >> 4;
  constexpr uint32_t LB = (LVL == 0) ? L0OFF : (LVL == 1) ? L1OFF
                        : (LVL == 2) ? L2OFF : L3OFF;
  constexpr uint32_t PBl = (LVL == 0) ? 4718592u : (LVL == 1) ? 1179648u
                         : (LVL == 2) ? 294912u : 73728u;
  constexpr float inv = 1.0f / (float)(1 << LVL);

  const int FX = (LVL < 3) ? (ci << (2 - LVL)) : (ci >> 1);
  const int FY = (LVL < 3) ? (cj << (2 - LVL)) : (cj >> 1);
  const int XU0 = FX - 4, YU0 = FY - 4;
  const char* lbase = ws + LB + (size_t)b * PBl;
  const char* zp = ws + ZPOFF;
  const char* f1b = ws + F1OFF;
  const int* perm = (const int*)(ws + PERMOFF);
  _Float16* scr = (_Float16*)(ws + SCROFF);

  const int row16 = lane & 15, kb = lane >> 4;
  const int nmt = (end - beg + 15) >> 4;

  for (int mt = 0; mt < nmt; ++mt) {
    // A-fragments for 16 pixels straight from L2
    half8 av[8];
    {
      const int i0 = beg + mt * 16 + row16;
      const int pv0 = (i0 < end) ? perm[i0] : perm[beg];
      const char* a0 = f1b + (size_t)pv0 * 512 + kb * 16;
#pragma unroll
      for (int k = 0; k < 8; ++k) av[k] = *(const half8*)(a0 + k * 64);
    }

    auto baddr = [&](int j) -> const char* {
      const int n = j * 16 + row16;
      const int sy = n / W, sx = n - sy * W;
      const int gy = YU0 + sy, gx = XU0 + sx;
      const bool val = (gy >= 0) & (gy < wl) & (gx >= 0) & (gx < wl);
      return (val ? (lbase + (((size_t)(gy * wl + gx)) << 9)) : zp) + kb * 16;
    };

    // software-pipelined j loop: load j+1 while MFMAing j
    half8 bc[8], bn[8];
    {
      const char* bp = baddr(0);
#pragma unroll
      for (int k = 0; k < 8; ++k) bc[k] = *(const half8*)(bp + k * 64);
    }
#pragma unroll 1
    for (int j = 0; j < ntiles; ++j) {
      if (j + 1 < ntiles) {
        const char* bp = baddr(j + 1);
#pragma unroll
        for (int k = 0; k < 8; ++k) bn[k] = *(const half8*)(bp + k * 64);
      }
      f32x4 acc = {0.f, 0.f, 0.f, 0.f};
#pragma unroll
      for (int k = 0; k < 8; ++k)
        acc = __builtin_amdgcn_mfma_f32_16x16x32_f16(av[k], bc[k], acc, 0, 0, 0);
      const int col = j * 16 + row16;
#pragma unroll
      for (int j4 = 0; j4 < 4; ++j4)
        dl[(kb * 4 + j4) * DLW + col] = (_Float16)acc[j4];
#pragma unroll
      for (int k = 0; k < 8; ++k) bc[k] = bn[k];
    }

    // epilogue: 4 lanes per pixel (same wave; lgkmcnt orders dl RAW)
    {
      const int p = lane >> 2, q = lane & 3;
      const int idx = beg + mt * 16 + p;
      if (idx < end) {
        const int pv = perm[idx];
        const int yx = pv - b * HW_;
        const float cx = cent[(size_t)b * 2 * HW_ + yx];
        const float cy = cent[(size_t)b * 2 * HW_ + HW_ + yx];
        const float cxl = cx * inv, cyl = cy * inv;
        const float fxl = floorf(cxl), fyl = floorf(cyl);
        const float wx1 = cxl - fxl, wy1 = cyl - fyl;
        const float wx0 = 1.f - wx1, wy0 = 1.f - wy1;
        const int sxp = (int)fxl - FX, syp = (int)fyl - FY;
        const _Float16* d = &dl[p * DLW];
        _Float16* so = scr + (size_t)pv * 324 + LVL * 81;
#pragma unroll
        for (int rr = 0; rr < 21; ++rr) {
          const int o = q + rr * 4;
          if (o < 81) {
            const int a = o / 9, bq = o - a * 9;   // a = x idx, bq = y idx
            const int n = (syp + bq) * W + sxp + a;
            const float d00 = (float)d[n], d10 = (float)d[n + 1];
            const float d01 = (float)d[n + W], d11 = (float)d[n + W + 1];
            so[o] = (_Float16)(wy0 * (wx0 * d00 + wx1 * d10) +
                               wy1 * (wx0 * d01 + wx1 * d11));
          }
        }
      }
    }
  }
}

__global__ __launch_bounds__(64, 4) void k_cell(char* __restrict__ ws,
                                                const float* __restrict__ cent) {
  __shared__ _Float16 dl[16 * DLW];   // 5.6 KB, private to this 1-wave block

  // XCD swizzle: bx&7 -> XCD; each XCD owns a contiguous 6-cell-row band of
  // one batch (L0 band ~1.4 MB + f1t band ~1.2 MB -> L2-resident per XCD).
  const int bx = blockIdx.x;           // 0..4607
  const int xcd = bx & 7, slot = bx >> 3;   // slot 0..575
  const int b = xcd >> 2, band = xcd & 3;
  const int lvl = slot / 144;
  const int rem = slot - lvl * 144;
  const int cjb = rem / 24, ci = rem - cjb * 24;
  const int cj = band * 6 + cjb;
  const int cell = b * 576 + cj * 24 + ci;

  const int* offs = (const int*)(ws + OFFOFF);
  const int beg = offs[cell], end = offs[cell + 1];
  if (beg == end) return;

  const int lane = threadIdx.x;
  switch (lvl) {
    case 0: cell_level<0>(ws, cent, b, ci, cj, beg, end, dl, lane); break;
    case 1: cell_level<1>(ws, cent, b, ci, cj, beg, end, dl, lane); break;
    case 2: cell_level<2>(ws, cent, b, ci, cj, beg, end, dl, lane); break;
    default: cell_level<3>(ws, cent, b, ci, cj, beg, end, dl, lane); break;
  }
}

// ---------- final transpose: scr[B*HW][324] f16 -> out[B][324][HW] f32 ----------
__global__ __launch_bounds__(256) void k_otrans(const _Float16* __restrict__ scr,
                                                float* __restrict__ out) {
  __shared__ float t[32][33];
  const int b = blockIdx.z;
  const int yx0 = blockIdx.x * 32, c0 = blockIdx.y * 32;
  const int tx = threadIdx.x, ty = threadIdx.y;
#pragma unroll
  for (int i = 0; i < 4; ++i) {
    const int yxi = ty + 8 * i, c = c0 + tx;
    t[yxi][tx] = (c < 324)
        ? (float)scr[((size_t)b * HW_ + yx0 + yxi) * 324 + c] : 0.f;
  }
  __syncthreads();
#pragma unroll
  for (int i = 0; i < 4; ++i) {
    const int c = c0 + ty + 8 * i;
    if (c < 324)
      out[((size_t)b * 324 + c) * HW_ + yx0 + tx] = t[tx][ty + 8 * i];
  }
}

extern "C" void kernel_launch(void* const* d_in, const int* in_sizes, int n_in,
                              void* d_out, int out_size, void* d_ws, size_t ws_size,
                              hipStream_t stream) {
  (void)in_sizes; (void)n_in; (void)out_size; (void)ws_size;
  const float* f1   = (const float*)d_in[0];
  const float* f2   = (const float*)d_in[1];
  const float* cent = (const float*)d_in[2];
  float* out = (float*)d_out;

  char* ws = (char*)d_ws;
  _Float16* f1t = (_Float16*)(ws + F1OFF);
  _Float16* L0  = (_Float16*)(ws + L0OFF);
  _Float16* L1  = (_Float16*)(ws + L1OFF);
  _Float16* L2  = (_Float16*)(ws + L2OFF);
  _Float16* L3  = (_Float16*)(ws + L3OFF);
  int* cnt    = (int*)(ws + CNTOFF);
  int* offs   = (int*)(ws + OFFOFF);
  int* cursor = (int*)(ws + CUROFF);
  int* perm   = (int*)(ws + PERMOFF);

  (void)hipMemsetAsync(ws + ZPOFF, 0, 512, stream);            // zero page
  (void)hipMemsetAsync(cnt, 0, 1152 * sizeof(int), stream);

  dim3 tb(32, 8, 1);
  dim3 tg(HW_ / 32, C_ / 32, B_);
  hipLaunchKernelGGL(k_transpose, tg, tb, 0, stream, f1, f1t, 0.0625f);
  hipLaunchKernelGGL(k_transpose, tg, tb, 0, stream, f2, L0, 1.0f);
  hipLaunchKernelGGL(k_pool, dim3(B_ * 48 * 48), dim3(256), 0, stream, L0, L1, 96, 96);
  hipLaunchKernelGGL(k_pool, dim3(B_ * 24 * 24), dim3(256), 0, stream, L1, L2, 48, 48);
  hipLaunchKernelGGL(k_pool, dim3(B_ * 12 * 12), dim3(256), 0, stream, L2, L3, 24, 24);

  hipLaunchKernelGGL(k_hist, dim3(72), dim3(256), 0, stream, cent, cnt);
  hipLaunchKernelGGL(k_scan, dim3(1), dim3(1024), 0, stream, cnt, offs, cursor);
  hipLaunchKernelGGL(k_scatter, dim3(72), dim3(256), 0, stream, cent, cursor, perm);

  hipLaunchKernelGGL(k_cell, dim3(4608), dim3(64), 0, stream, ws, cent);

  hipLaunchKernelGGL(k_otrans, dim3(HW_ / 32, 11, B_), tb, 0, stream,
                     (const _Float16*)(ws + SCROFF), out);
}

// Round 11
// 106.684 us; speedup vs baseline: 1.5066x; 1.1621x over previous
//
#include <hip/hip_runtime.h>
#include <stdint.h>

#define B_ 2
#define C_ 256
#define H_ 96
#define W_ 96
#define HW_ (H_*W_)

typedef _Float16 half8 __attribute__((ext_vector_type(8)));
typedef float f32x4 __attribute__((ext_vector_type(4)));

// ---- workspace byte layout ----
#define ZPOFF   0u          // 512 B zero page
#define CNTOFF  512u        // int cnt[1152]
#define PERMOFF 5120u       // int perm[1152][96]
#define F1OFF   447488u     // f16 (B,HW,C) f1, pre-scaled 1/16
#define L0OFF   9884672u
#define L1OFF   19321856u
#define L2OFF   21681152u
#define L3OFF   22270976u
#define SCROFF  22418432u   // f16 scr[B*HW][324]
// end: 34362368

#define CAP 96
#define DLW 176

// ---------- fused transpose: f1 -> f1t (scaled), f2 -> L0 ----------
__global__ __launch_bounds__(256) void k_tr2(const float* __restrict__ f1,
                                             const float* __restrict__ f2,
                                             _Float16* __restrict__ f1t,
                                             _Float16* __restrict__ L0h) {
  __shared__ float t[32][33];
  const int z = blockIdx.z;
  const int b = z & 1;
  const bool is2 = (z >> 1) != 0;
  const float* in = is2 ? f2 : f1;
  _Float16* out = is2 ? L0h : f1t;
  const float scale = is2 ? 1.0f : 0.0625f;

  const int p0 = blockIdx.x * 32, c0 = blockIdx.y * 32;
  const int tx = threadIdx.x, ty = threadIdx.y;
  const float* src = in + ((size_t)b * C_ + c0) * HW_ + p0;
#pragma unroll
  for (int i = 0; i < 4; ++i)
    t[ty + 8 * i][tx] = src[(size_t)(ty + 8 * i) * HW_ + tx];
  __syncthreads();
  _Float16* dst = out + ((size_t)b * HW_ + p0) * C_ + c0;
#pragma unroll
  for (int i = 0; i < 4; ++i)
    dst[(size_t)(ty + 8 * i) * C_ + tx] = (_Float16)(t[tx][ty + 8 * i] * scale);
}

// ---------- fused pools: L1, L2, L3 straight from L0 ----------
__global__ __launch_bounds__(256) void k_pool3(const _Float16* __restrict__ L0,
                                               _Float16* __restrict__ L1,
                                               _Float16* __restrict__ L2,
                                               _Float16* __restrict__ L3) {
  int idx = blockIdx.x;
  const int X = idx % 12; idx /= 12;
  const int Y = idx % 12; const int b = idx / 12;
  const int c = threadIdx.x;

  const _Float16* base = L0 + (((size_t)b * 96 + 8 * Y) * 96 + 8 * X) * C_ + c;
  float s1[4][4];
#pragma unroll
  for (int i = 0; i < 4; ++i)
#pragma unroll
    for (int j = 0; j < 4; ++j) {
      const _Float16* p = base + ((size_t)(2 * i) * 96 + 2 * j) * C_;
      s1[i][j] = ((float)p[0] + (float)p[C_] +
                  (float)p[96 * C_] + (float)p[96 * C_ + C_]) * 0.25f;
    }
#pragma unroll
  for (int i = 0; i < 4; ++i)
#pragma unroll
    for (int j = 0; j < 4; ++j)
      L1[(((size_t)b * 48 + 4 * Y + i) * 48 + 4 * X + j) * C_ + c] = (_Float16)s1[i][j];

  float s2[2][2];
#pragma unroll
  for (int i = 0; i < 2; ++i)
#pragma unroll
    for (int j = 0; j < 2; ++j) {
      s2[i][j] = (s1[2 * i][2 * j] + s1[2 * i][2 * j + 1] +
                  s1[2 * i + 1][2 * j] + s1[2 * i + 1][2 * j + 1]) * 0.25f;
      L2[(((size_t)b * 24 + 2 * Y + i) * 24 + 2 * X + j) * C_ + c] = (_Float16)s2[i][j];
    }

  const float s3 = (s2[0][0] + s2[0][1] + s2[1][0] + s2[1][1]) * 0.25f;
  L3[(((size_t)b * 12 + Y) * 12 + X) * C_ + c] = (_Float16)s3;
}

// ---------- bucket: one pass, fixed capacity ----------
__global__ __launch_bounds__(256) void k_bucket(const float* __restrict__ cent,
                                                int* __restrict__ cnt,
                                                int* __restrict__ perm) {
  const int t = blockIdx.x * 256 + threadIdx.x;
  const int b = t / HW_, yx = t - b * HW_;
  const float cx = cent[(size_t)b * 2 * HW_ + yx];
  const float cy = cent[(size_t)b * 2 * HW_ + HW_ + yx];
  int ci = (int)(cx * 0.25f); ci = min(max(ci, 0), 23);
  int cj = (int)(cy * 0.25f); cj = min(max(cj, 0), 23);
  const int cell = b * 576 + cj * 24 + ci;
  const int pos = atomicAdd(&cnt[cell], 1);
  if (pos < CAP) perm[cell * CAP + pos] = t;
}

// ---------- per-(cell,level) single-wave GEMM + epilogue ----------
template <int LVL>
__device__ __forceinline__ void cell_level(char* __restrict__ ws,
                                           const float* __restrict__ cent,
                                           int b, int ci, int cj,
                                           const int* __restrict__ pc, int npix,
                                           _Float16* __restrict__ dl, int lane) {
  constexpr int wl = 96 >> LVL;
  constexpr int W = (LVL == 0) ? 13 : (LVL == 1) ? 11 : 10;
  constexpr int N = W * W;
  constexpr int ntiles = (N + 15) >> 4;
  constexpr uint32_t LB = (LVL == 0) ? L0OFF : (LVL == 1) ? L1OFF
                        : (LVL == 2) ? L2OFF : L3OFF;
  constexpr uint32_t PBl = (LVL == 0) ? 4718592u : (LVL == 1) ? 1179648u
                         : (LVL == 2) ? 294912u : 73728u;
  constexpr float inv = 1.0f / (float)(1 << LVL);

  const int FX = (LVL < 3) ? (ci << (2 - LVL)) : (ci >> 1);
  const int FY = (LVL < 3) ? (cj << (2 - LVL)) : (cj >> 1);
  const int XU0 = FX - 4, YU0 = FY - 4;
  const char* lbase = ws + LB + (size_t)b * PBl;
  const char* zp = ws + ZPOFF;
  const char* f1b = ws + F1OFF;
  _Float16* scr = (_Float16*)(ws + SCROFF);

  const int row16 = lane & 15, kb = lane >> 4;
  const int nmt = (npix + 15) >> 4;

  for (int mt = 0; mt < nmt; ++mt) {
    // A-fragments for 16 pixels straight from L2
    half8 av[8];
    {
      const int i0 = mt * 16 + row16;
      const int pv0 = (i0 < npix) ? pc[i0] : pc[0];
      const char* a0 = f1b + (size_t)pv0 * 512 + kb * 16;
#pragma unroll
      for (int k = 0; k < 8; ++k) av[k] = *(const half8*)(a0 + k * 64);
    }

    auto baddr = [&](int j) -> const char* {
      const int n = j * 16 + row16;
      const int sy = n / W, sx = n - sy * W;
      const int gy = YU0 + sy, gx = XU0 + sx;
      const bool val = (gy >= 0) & (gy < wl) & (gx >= 0) & (gx < wl);
      return (val ? (lbase + (((size_t)(gy * wl + gx)) << 9)) : zp) + kb * 16;
    };

    // 3-buffer pipeline, fully unrolled (ntiles constexpr): 2 tiles in flight
    half8 bb[3][8];
    {
      const char* bp = baddr(0);
#pragma unroll
      for (int k = 0; k < 8; ++k) bb[0][k] = *(const half8*)(bp + k * 64);
    }
    if (ntiles > 1) {
      const char* bp = baddr(1);
#pragma unroll
      for (int k = 0; k < 8; ++k) bb[1][k] = *(const half8*)(bp + k * 64);
    }
#pragma unroll
    for (int j = 0; j < ntiles; ++j) {
      if (j + 2 < ntiles) {
        const char* bp = baddr(j + 2);
#pragma unroll
        for (int k = 0; k < 8; ++k) bb[(j + 2) % 3][k] = *(const half8*)(bp + k * 64);
      }
      f32x4 acc = {0.f, 0.f, 0.f, 0.f};
#pragma unroll
      for (int k = 0; k < 8; ++k)
        acc = __builtin_amdgcn_mfma_f32_16x16x32_f16(av[k], bb[j % 3][k], acc, 0, 0, 0);
      const int col = j * 16 + row16;
#pragma unroll
      for (int j4 = 0; j4 < 4; ++j4)
        dl[(kb * 4 + j4) * DLW + col] = (_Float16)acc[j4];
    }

    // epilogue: 4 lanes per pixel (same wave; lgkmcnt orders dl RAW)
    {
      const int p = lane >> 2, q = lane & 3;
      const int idx = mt * 16 + p;
      if (idx < npix) {
        const int pv = pc[idx];
        const int yx = pv - b * HW_;
        const float cx = cent[(size_t)b * 2 * HW_ + yx];
        const float cy = cent[(size_t)b * 2 * HW_ + HW_ + yx];
        const float cxl = cx * inv, cyl = cy * inv;
        const float fxl = floorf(cxl), fyl = floorf(cyl);
        const float wx1 = cxl - fxl, wy1 = cyl - fyl;
        const float wx0 = 1.f - wx1, wy0 = 1.f - wy1;
        const int sxp = (int)fxl - FX, syp = (int)fyl - FY;
        const _Float16* d = &dl[p * DLW];
        _Float16* so = scr + (size_t)pv * 324 + LVL * 81;
#pragma unroll
        for (int rr = 0; rr < 21; ++rr) {
          const int o = q + rr * 4;
          if (o < 81) {
            const int a = o / 9, bq = o - a * 9;   // a = x idx, bq = y idx
            const int n = (syp + bq) * W + sxp + a;
            const float d00 = (float)d[n], d10 = (float)d[n + 1];
            const float d01 = (float)d[n + W], d11 = (float)d[n + W + 1];
            so[o] = (_Float16)(wy0 * (wx0 * d00 + wx1 * d10) +
                               wy1 * (wx0 * d01 + wx1 * d11));
          }
        }
      }
    }
  }
}

__global__ __launch_bounds__(64, 3) void k_cell(char* __restrict__ ws,
                                                const float* __restrict__ cent) {
  __shared__ _Float16 dl[16 * DLW];   // 5.6 KB, private to this 1-wave block

  // XCD swizzle: bx&7 -> XCD; each XCD owns a contiguous 6-cell-row band of
  // one batch; levels ordered longest-first within each band.
  const int bx = blockIdx.x;                 // 0..4607
  const int xcd = bx & 7, slot = bx >> 3;    // slot 0..575
  const int b = xcd >> 2, band = xcd & 3;
  const int lvl = slot / 144;
  const int rem = slot - lvl * 144;
  const int cjb = rem / 24, ci = rem - cjb * 24;
  const int cj = band * 6 + cjb;
  const int cell = b * 576 + cj * 24 + ci;

  const int* cnt = (const int*)(ws + CNTOFF);
  const int npix = min(cnt[cell], CAP);
  if (npix == 0) return;
  const int* pc = (const int*)(ws + PERMOFF) + cell * CAP;

  const int lane = threadIdx.x;
  switch (lvl) {
    case 0: cell_level<0>(ws, cent, b, ci, cj, pc, npix, dl, lane); break;
    case 1: cell_level<1>(ws, cent, b, ci, cj, pc, npix, dl, lane); break;
    case 2: cell_level<2>(ws, cent, b, ci, cj, pc, npix, dl, lane); break;
    default: cell_level<3>(ws, cent, b, ci, cj, pc, npix, dl, lane); break;
  }
}

// ---------- final transpose: scr[B*HW][324] f16 -> out[B][324][HW] f32 ----------
__global__ __launch_bounds__(256) void k_otrans(const _Float16* __restrict__ scr,
                                                float* __restrict__ out) {
  __shared__ float t[32][33];
  const int b = blockIdx.z;
  const int yx0 = blockIdx.x * 32, c0 = blockIdx.y * 32;
  const int tx = threadIdx.x, ty = threadIdx.y;
#pragma unroll
  for (int i = 0; i < 4; ++i) {
    const int yxi = ty + 8 * i, c = c0 + tx;
    t[yxi][tx] = (c < 324)
        ? (float)scr[((size_t)b * HW_ + yx0 + yxi) * 324 + c] : 0.f;
  }
  __syncthreads();
#pragma unroll
  for (int i = 0; i < 4; ++i) {
    const int c = c0 + ty + 8 * i;
    if (c < 324)
      out[((size_t)b * 324 + c) * HW_ + yx0 + tx] = t[tx][ty + 8 * i];
  }
}

extern "C" void kernel_launch(void* const* d_in, const int* in_sizes, int n_in,
                              void* d_out, int out_size, void* d_ws, size_t ws_size,
                              hipStream_t stream) {
  (void)in_sizes; (void)n_in; (void)out_size; (void)ws_size;
  const float* f1   = (const float*)d_in[0];
  const float* f2   = (const float*)d_in[1];
  const float* cent = (const float*)d_in[2];
  float* out = (float*)d_out;

  char* ws = (char*)d_ws;
  _Float16* f1t = (_Float16*)(ws + F1OFF);
  _Float16* L0  = (_Float16*)(ws + L0OFF);
  _Float16* L1  = (_Float16*)(ws + L1OFF);
  _Float16* L2  = (_Float16*)(ws + L2OFF);
  _Float16* L3  = (_Float16*)(ws + L3OFF);
  int* cnt  = (int*)(ws + CNTOFF);
  int* perm = (int*)(ws + PERMOFF);

  (void)hipMemsetAsync(ws, 0, 5120, stream);   // zero page + cnt

  hipLaunchKernelGGL(k_bucket, dim3(72), dim3(256), 0, stream, cent, cnt, perm);

  dim3 tb(32, 8, 1);
  hipLaunchKernelGGL(k_tr2, dim3(HW_ / 32, C_ / 32, 2 * B_), tb, 0, stream,
                     f1, f2, f1t, L0);
  hipLaunchKernelGGL(k_pool3, dim3(B_ * 12 * 12), dim3(256), 0, stream,
                     L0, L1, L2, L3);

  hipLaunchKernelGGL(k_cell, dim3(4608), dim3(64), 0, stream, ws, cent);

  hipLaunchKernelGGL(k_otrans, dim3(HW_ / 32, 11, B_), tb, 0, stream,
                     (const _Float16*)(ws + SCROFF), out);
}